// Round 6
// baseline (223.394 us; speedup 1.0000x reference)
//
#include <hip/hip_runtime.h>
#include <hip/hip_bf16.h>
#include <cstdint>

#define N_BATCH 2
#define C_IN 256
#define DYN_CH 34
#define CLS_CH 720
#define NUM_CLASSES 80
#define NCOMB 48

#define P0c 15200
#define P1c 3800
#define M0c 30400
#define M1c 7600
#define MT0c 119
#define MT1c 30
#define CT0c 475
#define CT1c 119

typedef __attribute__((ext_vector_type(8))) short short8;   // 8 bf16
typedef __attribute__((ext_vector_type(4))) float f32x4;

typedef const unsigned int __attribute__((address_space(1)))* gas1_t;
typedef unsigned int __attribute__((address_space(3)))* las3_t;

__device__ __forceinline__ void async_ld16(const void* g, void* l) {
  __builtin_amdgcn_global_load_lds((gas1_t)g, (las3_t)l, 16, 0, 0);
}

// ---------------- pack_feat: all 4 feature packs (tiled layout) + weight packs
__global__ __launch_bounds__(256) void pack_feat(
    const float* __restrict__ cls0, const float* __restrict__ cls1,
    const float* __restrict__ reg0, const float* __restrict__ reg1,
    const float* __restrict__ cls_w, const float* __restrict__ dyn_w,
    const float* __restrict__ reg_w, __hip_bfloat16* __restrict__ a0,
    __hip_bfloat16* __restrict__ a1, __hip_bfloat16* __restrict__ r0,
    __hip_bfloat16* __restrict__ r1, __hip_bfloat16* __restrict__ bpack,
    __hip_bfloat16* __restrict__ wpack) {
  int b = blockIdx.x;
  if (b >= 2384) {
    b -= 2384;
    if (b < 90) {  // cls weights -> bpack [ntile][kcg][och]
      int u = b * 256 + threadIdx.x;
      if (u >= 9 * 32 * 80) return;
      int ntile = u / 2560;
      int rem = u % 2560;
      int kcg = rem / 80;
      int ochl = rem % 80;
      int och = ntile * 80 + ochl;
      const float* wr = cls_w + (size_t)och * C_IN + kcg * 8;
      __hip_bfloat16 tmp[8];
#pragma unroll
      for (int c = 0; c < 8; ++c) tmp[c] = __float2bfloat16(wr[c]);
      *(uint4*)(bpack + (size_t)u * 8) = *(const uint4*)tmp;
    } else {  // dyn+reg weights -> wpack swizzled [chunk][n][slot]
      int u = (b - 90) * 256 + threadIdx.x;
      if (u >= 13824) return;
      int j = u / 768;
      int r = u % 768;
      int n = r / 16;
      int s = r % 16;
      int ku = j * 16 + (s ^ (n & 7));
      int k0 = ku * 8;
      int tap = k0 >> 8;
      int c0 = k0 & 255;
      __hip_bfloat16 tmp[8];
#pragma unroll
      for (int i = 0; i < 8; ++i) {
        int c = c0 + i;
        float v = 0.f;
        if (n < DYN_CH) v = dyn_w[((size_t)n * C_IN + c) * 9 + tap];
        else if (n < DYN_CH + 4 && tap == 4)
          v = reg_w[(size_t)(n - DYN_CH) * C_IN + c];
        tmp[i] = __float2bfloat16(v);
      }
      *(uint4*)(wpack + (size_t)u * 8) = *(const uint4*)tmp;
    }
    return;
  }
  int j = b & 7;
  int mtg = b >> 3;
  const float* src;
  __hip_bfloat16* dst;
  int P, Mtot, mtile;
  if (mtg < 119)      { src = cls0; dst = a0; P = P0c; Mtot = M0c; mtile = mtg; }
  else if (mtg < 149) { src = cls1; dst = a1; P = P1c; Mtot = M1c; mtile = mtg - 119; }
  else if (mtg < 268) { src = reg0; dst = r0; P = P0c; Mtot = M0c; mtile = mtg - 149; }
  else                { src = reg1; dst = r1; P = P1c; Mtot = M1c; mtile = mtg - 268; }
  int wave = threadIdx.x >> 6;
  int lane = threadIdx.x & 63;
  int kcg = j * 4 + wave;
  int c0 = kcg * 8;
  int m4 = mtile * 256 + lane * 4;
  uint4* du = (uint4*)dst + (size_t)mtile * 8192 + (size_t)kcg * 256 + lane * 4;
  if (m4 < Mtot) {
    int n = m4 / P;
    int p = m4 - n * P;
    const float* sp = src + ((size_t)n * C_IN + c0) * P + p;
    float4 f[8];
#pragma unroll
    for (int c = 0; c < 8; ++c) f[c] = *(const float4*)(sp + (size_t)c * P);
#pragma unroll
    for (int i = 0; i < 4; ++i) {
      union { uint4 u; __hip_bfloat16 h[8]; } o;
#pragma unroll
      for (int c = 0; c < 8; ++c) {
        float v = (i == 0) ? f[c].x : (i == 1) ? f[c].y : (i == 2) ? f[c].z : f[c].w;
        o.h[c] = __float2bfloat16(v);
      }
      du[i] = o.u;
    }
  } else {
    uint4 z = {0u, 0u, 0u, 0u};
#pragma unroll
    for (int i = 0; i < 4; ++i) du[i] = z;
  }
}

// ------------------- cls 1x1 bf16 MFMA GEMM -> bf16 map pixel-major [m][720]
// XCD-aware grid; B-ntile staged to LDS once; barrier-free K-loop with
// direct-global A fragments; 8 waves x acc[2][5].
// EPILOGUE: operands SWAPPED in the MFMA (mfma(b,a)) so the C/D mapping
// (col=lane&15, row=(lane>>4)*4+reg) puts och in the 4 consecutive regs and
// the pixel in l15 -> each lane packs 4 memory-adjacent bf16 into one uint2
// store: 10 stores/thread instead of 40 (28M -> 7M VMEM store instrs,
// ~11 us of SIMD issue bandwidth reclaimed). Numerics identical.
__global__ __launch_bounds__(512) void cls_gemm_mfma(
    const uint4* __restrict__ Ap0, const uint4* __restrict__ Ap1,
    const uint4* __restrict__ Bp, __hip_bfloat16* __restrict__ out0,
    __hip_bfloat16* __restrict__ out1) {
  __shared__ uint4 Bsh[2560];
  int bb = blockIdx.x;
  int g = bb & 7;
  int loc = bb >> 3;          // [0,171) = 19 mtiles x 9 ntiles
  int lm = loc / 9;
  int ntile = loc - lm * 9;
  int mtile = g * 19 + lm;
  if (mtile >= MT0c + MT1c) return;
  int tid = threadIdx.x;
  int w = tid >> 6;
  int lane = tid & 63;
  int l15 = lane & 15;
  int kq = lane >> 4;

  const uint4* Ap;
  __hip_bfloat16* out;
  int Mtot;
  if (mtile < MT0c) { Ap = Ap0; out = out0; Mtot = M0c; }
  else              { mtile -= MT0c; Ap = Ap1; out = out1; Mtot = M1c; }

  const uint4* Ab = Ap + (size_t)mtile * 8192;
  const uint4* Bb = Bp + (size_t)ntile * 2560;

  // stage the whole B-ntile once (2560 uint4 = 40 KB)
#pragma unroll
  for (int i = 0; i < 5; ++i)
    async_ld16(Bb + i * 512 + w * 64 + lane, &Bsh[i * 512 + w * 64]);
  __syncthreads();

  f32x4 acc[2][5];
#pragma unroll
  for (int i = 0; i < 2; ++i)
#pragma unroll
    for (int j = 0; j < 5; ++j) acc[i][j] = (f32x4)0.f;

  const uint4* Abase = Ab + kq * 256 + w * 32 + l15;
#pragma unroll 2
  for (int kb = 0; kb < 8; ++kb) {
    uint4 a[2];
#pragma unroll
    for (int mi = 0; mi < 2; ++mi) a[mi] = Abase[kb * 1024 + mi * 16];
    short8 b[5];
    const uint4* Br = &Bsh[kb * 320 + kq * 80 + l15];
#pragma unroll
    for (int ni = 0; ni < 5; ++ni) b[ni] = *(const short8*)&Br[ni * 16];
#pragma unroll
    for (int mi = 0; mi < 2; ++mi)
#pragma unroll
      for (int ni = 0; ni < 5; ++ni)
        acc[mi][ni] = __builtin_amdgcn_mfma_f32_16x16x32_bf16(
            b[ni], *(const short8*)&a[mi], acc[mi][ni], 0, 0, 0);
  }

  // swapped layout: lane (kq,l15) holds och = ni*16 + kq*4 + r (r = reg 0..3)
  // for pixel px = gbase + mi*16 + l15  ->  4 adjacent bf16 = 1 uint2 store.
  int gbase = mtile * 256 + w * 32;
#pragma unroll
  for (int mi = 0; mi < 2; ++mi) {
    int px = gbase + mi * 16 + l15;
    if (px >= Mtot) continue;
    __hip_bfloat16* orow = out + (size_t)px * CLS_CH + ntile * 80 + kq * 4;
#pragma unroll
    for (int ni = 0; ni < 5; ++ni) {
      union { uint2 u; __hip_bfloat16 h[4]; } o;
#pragma unroll
      for (int r = 0; r < 4; ++r) o.h[r] = __float2bfloat16(acc[mi][ni][r]);
      *(uint2*)(orow + ni * 16) = o.u;
    }
  }
}

// ---------- dyn3x3 + reg1x1 fused implicit-GEMM MFMA, FULL-K (no split-K).
// Each block accumulates all 18 weight chunks (9 taps x 2 C-halves) -> part is
// written ONCE, pre-summed. Bijective XCD chunking (74+{0,1} per XCD) keeps
// tap re-reads L2-local and matches decode's partition.
__global__ __launch_bounds__(256) void dyn_reg_conv_mfma(
    const uint4* __restrict__ rp0, const uint4* __restrict__ rp1,
    const uint4* __restrict__ wp, float* __restrict__ part0,
    float* __restrict__ part1) {
  __shared__ uint4 Bs[768];
  int g = blockIdx.x & 7;
  int i = blockIdx.x >> 3;         // [0,75)
  int cnt = 74 + (g < 2 ? 1 : 0);  // 594 = 8*74 + 2
  if (i >= cnt) return;            // block-uniform exit: no barrier hazard
  int bx = g * 74 + (g < 2 ? g : 2) + i;   // [0,594), contiguous per XCD
  int tid = threadIdx.x;
  int wave = tid >> 6;
  int lane = tid & 63;
  int l15 = lane & 15;
  int kq = lane >> 4;

  const uint4* rp;
  float* part;
  int Mtot, P, W, H;
  if (bx < CT0c) { rp = rp0; part = part0; Mtot = M0c; P = P0c; W = 152; H = 100; }
  else { bx -= CT0c; rp = rp1; part = part1; Mtot = M1c; P = P1c; W = 76; H = 50; }

  int m = bx * 64 + wave * 16 + l15;
  bool mval = (m < Mtot);
  int mc = mval ? m : 0;
  int n = mc / P;
  int rem = mc - n * P;
  int y = rem / W;
  int x = rem - y * W;

  f32x4 acc[3];
#pragma unroll
  for (int q = 0; q < 3; ++q) acc[q] = (f32x4)0.f;

  for (int j = 0; j < 18; ++j) {
    const uint4* wsrc = wp + (size_t)j * 768 + wave * 192;
#pragma unroll
    for (int q = 0; q < 3; ++q)
      async_ld16(wsrc + q * 64 + lane, &Bs[wave * 192 + q * 64]);

    int tap = j >> 1;
    int cb8 = (j & 1) * 16;
    int dy = tap / 3 - 1, dx = tap % 3 - 1;
    int sy = y + dy, sx = x + dx;
    bool val = mval && ((unsigned)sy < (unsigned)H) && ((unsigned)sx < (unsigned)W);
    int sm = m + dy * W + dx;
    int smc = val ? sm : 0;
    size_t tbase = (size_t)(smc >> 8) * 8192 + (smc & 255);
    uint4 a[4];
#pragma unroll
    for (int t = 0; t < 4; ++t) {
      uint4 v = {0u, 0u, 0u, 0u};
      if (val) v = rp[tbase + (size_t)(cb8 + t * 4 + kq) * 256];
      a[t] = v;
    }
    __syncthreads();
#pragma unroll
    for (int t = 0; t < 4; ++t) {
#pragma unroll
      for (int ni = 0; ni < 3; ++ni) {
        int nn = ni * 16 + l15;
        short8 bf = *(const short8*)&Bs[nn * 16 + ((t * 4 + kq) ^ (nn & 7))];
        acc[ni] = __builtin_amdgcn_mfma_f32_16x16x32_bf16(
            *(short8*)&a[t], bf, acc[ni], 0, 0, 0);
      }
    }
    __syncthreads();
  }

  int mrow = bx * 64 + wave * 16 + kq * 4;
#pragma unroll
  for (int r = 0; r < 4; ++r) {
    int mm = mrow + r;
    if (mm >= Mtot) continue;
    float* dst = part + (size_t)mm * NCOMB + l15;
#pragma unroll
    for (int ni = 0; ni < 3; ++ni) dst[ni * 16] = acc[ni][r];
  }
}

// -------------------- bilinear sample of combined-map channel (pre-summed)
__device__ __forceinline__ float samp(const float* __restrict__ part,
                                      int nbase, int W, int H,
                                      float px, float py, int ch) {
  float xc = fminf(fmaxf(px, 0.f), (float)(W - 1));
  float yc = fminf(fmaxf(py, 0.f), (float)(H - 1));
  float x0f = floorf(xc), y0f = floorf(yc);
  float fx = xc - x0f, fy = yc - y0f;
  int x0 = (int)x0f, y0 = (int)y0f;
  int x1 = min(x0 + 1, W - 1), y1 = min(y0 + 1, H - 1);
  float v00 = part[(size_t)(nbase + y0 * W + x0) * NCOMB + ch];
  float v01 = part[(size_t)(nbase + y0 * W + x1) * NCOMB + ch];
  float v10 = part[(size_t)(nbase + y1 * W + x0) * NCOMB + ch];
  float v11 = part[(size_t)(nbase + y1 * W + x1) * NCOMB + ch];
  return v00 * (1.f - fx) * (1.f - fy) + v01 * fx * (1.f - fy) +
         v10 * (1.f - fx) * fy + v11 * fx * fy;
}

// ---------------- decode, both levels fused; XCD chunking EXACTLY matches
// conv's (74+{0,1} units per XCD) -> pr reads and bilinear corner reads hit
// the L2 where conv just wrote that m-range. part is pre-summed: 10 float4
// pr-loads and 4 loads per bilinear point.
__global__ __launch_bounds__(64) void decode(
    const float* __restrict__ part0, const float* __restrict__ part1,
    const float* __restrict__ dyn_b, const float* __restrict__ anchor0,
    const float* __restrict__ anchor1, float* __restrict__ out_coarse0,
    float* __restrict__ out_coarse1, float* __restrict__ out_regbox0,
    float* __restrict__ out_regbox1, int4* __restrict__ sidx0,
    float4* __restrict__ swt0, int4* __restrict__ sidx1,
    float4* __restrict__ swt1) {
  int g = blockIdx.x & 7;
  int i = blockIdx.x >> 3;         // [0,75)
  int cnt = 74 + (g < 2 ? 1 : 0);
  if (i >= cnt) return;
  int u = g * 74 + (g < 2 ? g : 2) + i;   // [0,594)
  const float* part;
  const float* anchor;
  float* out_coarse;
  float* out_regbox;
  int4* sidx;
  float4* swt;
  int Mtot, H, W, P, level, m;
  if (u < 475) {
    part = part0; anchor = anchor0; out_coarse = out_coarse0;
    out_regbox = out_regbox0; sidx = sidx0; swt = swt0;
    Mtot = M0c; H = 100; W = 152; P = P0c; level = 0;
    m = u * 64 + threadIdx.x;
  } else {
    part = part1; anchor = anchor1; out_coarse = out_coarse1;
    out_regbox = out_regbox1; sidx = sidx1; swt = swt1;
    Mtot = M1c; H = 50; W = 76; P = P1c; level = 1;
    m = (u - 475) * 64 + threadIdx.x;
  }
  if (m >= Mtot) return;
  int n = m / P;
  int p = m - n * P;
  float pr[40];
  {
    const float4* q0 = (const float4*)(part + (size_t)m * NCOMB);
#pragma unroll
    for (int o4 = 0; o4 < 10; ++o4) {
      float4 a = q0[o4];
      pr[4 * o4 + 0] = a.x;
      pr[4 * o4 + 1] = a.y;
      pr[4 * o4 + 2] = a.z;
      pr[4 * o4 + 3] = a.w;
    }
#pragma unroll
    for (int o = 0; o < DYN_CH; ++o) pr[o] += dyn_b[o];
  }
  const float* an = anchor + (size_t)n * 4 * P + p;
  float cb[4];
#pragma unroll
  for (int k = 0; k < 4; ++k) cb[k] = an[(size_t)k * P] + pr[k];
  float* oc = out_coarse + (size_t)n * 4 * P + p;
#pragma unroll
  for (int k = 0; k < 4; ++k) oc[(size_t)k * P] = cb[k];

  float thr_y = (cb[3] - cb[1]) * 0.25f;
  float thr_x = (cb[2] - cb[0]) * 0.25f;
  float bo[4];
#pragma unroll
  for (int j = 0; j < 4; ++j) {
    float thr = (j & 1) ? thr_x : thr_y;
    float b = pr[4 + j];
    float extra = fmaxf(b - thr, 0.f) + fminf(b + thr, 0.f);
    bo[j] = b - extra;
  }
  float cx = 0.5f * (cb[0] + cb[2]);
  float cy = 0.5f * (cb[1] + cb[3]);
  float bp[8] = {cb[0], cy + bo[0], cx + bo[1], cb[1],
                 cb[2], cy + bo[2], cx + bo[3], cb[3]};

  int nbase = n * P;
  int nbaseLo = n * P0c;
  float rb[4];
#pragma unroll
  for (int pt = 0; pt < 4; ++pt) {
    float hi = samp(part, nbase, W, H, bp[2 * pt], bp[2 * pt + 1],
                    DYN_CH + pt);
    float val;
    if (level == 0) {
      val = hi;
    } else {
      float lo = 0.5f * samp(part0, nbaseLo, 152, 100, bp[2 * pt] * 2.f,
                             bp[2 * pt + 1] * 2.f, DYN_CH + pt);
      float e0 = pr[26 + 2 * pt], e1 = pr[26 + 2 * pt + 1];
      float mx = fmaxf(e0, e1);
      float w0 = expf(e0 - mx), w1 = expf(e1 - mx);
      val = (lo * w0 + hi * w1) / (w0 + w1);
    }
    rb[pt] = val;
  }
  float* orb = out_regbox + (size_t)n * 4 * P + p;
  orb[0] = bp[0] + rb[0];
  orb[(size_t)P] = bp[3] + rb[1];
  orb[(size_t)2 * P] = bp[4] + rb[2];
  orb[(size_t)3 * P] = bp[7] + rb[3];

  float sx[9] = {cb[0], cb[0], cb[0], cx, cx, cx, cb[2], cb[2], cb[2]};
  float sy[9] = {cb[1], cy, cb[3], cb[1], cy, cb[3], cb[1], cy, cb[3]};
#pragma unroll
  for (int k = 0; k < 9; ++k) {
    float px = sx[k] + pr[8 + 2 * k];
    float py = sy[k] + pr[8 + 2 * k + 1];
    float xc = fminf(fmaxf(px, 0.f), (float)(W - 1));
    float yc = fminf(fmaxf(py, 0.f), (float)(H - 1));
    float x0f = floorf(xc), y0f = floorf(yc);
    float fx = xc - x0f, fy = yc - y0f;
    int x0 = (int)x0f, y0 = (int)y0f;
    int x1 = min(x0 + 1, W - 1), y1 = min(y0 + 1, H - 1);
    int4 iv;
    iv.x = (nbase + y0 * W + x0) * CLS_CH + k * 80;
    iv.y = (x1 - x0) * CLS_CH;
    iv.z = (y1 - y0) * W * CLS_CH;
    iv.w = 0;
    sidx[(size_t)k * Mtot + m] = iv;
    float4 wv = {(1.f - fx) * (1.f - fy), fx * (1.f - fy), (1.f - fx) * fy,
                 fx * fy};
    swt[(size_t)k * Mtot + m] = wv;
  }
}

// ------------- gather: wave = 1 px. lane = (pt-subgroup sub=lane/20,
// class-quad cl=lane%20): 60/64 lanes active, uint2 (4-class) map loads,
// 3 outer iters cover 9 pts -> 18 VMEM insts/px-wave.
// Cross-subgroup reduce via 8 shfls (lanes cl, cl+20, cl+40).
__global__ __launch_bounds__(256) void cls_gather_f(
    const __hip_bfloat16* __restrict__ map0,
    const __hip_bfloat16* __restrict__ map1, const int4* __restrict__ sidx0,
    const float4* __restrict__ swt0, const int4* __restrict__ sidx1,
    const float4* __restrict__ swt1, const float* __restrict__ bias,
    float* __restrict__ outc0, float* __restrict__ outc1) {
  __shared__ float lds[NUM_CLASSES * 5];
  int b = (blockIdx.x & 7) * 1188 + (blockIdx.x >> 3);
  if (b >= 9500) return;
  const __hip_bfloat16* map;
  const int4* sidx;
  const float4* swt;
  float* out;
  int Mtot, P;
  if (b < 7600) { map = map0; sidx = sidx0; swt = swt0; out = outc0; Mtot = M0c; P = P0c; }
  else { b -= 7600; map = map1; sidx = sidx1; swt = swt1; out = outc1; Mtot = M1c; P = P1c; }
  int lane = threadIdx.x & 63;
  int wv = threadIdx.x >> 6;
  int m = b * 4 + wv;  // P,M div by 4: no tail, no n-straddle per block

  int sub = lane / 20;
  if (sub > 2) sub = 2;       // lanes 60..63 duplicate sub=2 (results unused)
  int cl = lane % 20;
  int c4 = cl * 4;

  float a0 = 0.f, a1 = 0.f, a2 = 0.f, a3 = 0.f;
#pragma unroll
  for (int g = 0; g < 3; ++g) {
    int pt = g * 3 + sub;
    int4 iv = sidx[(size_t)pt * Mtot + m];
    float4 wt = swt[(size_t)pt * Mtot + m];
    const __hip_bfloat16* pl = map + iv.x + c4;
    uint2 t00 = *(const uint2*)(pl);
    uint2 t01 = *(const uint2*)(pl + iv.y);
    uint2 t10 = *(const uint2*)(pl + iv.z);
    uint2 t11 = *(const uint2*)(pl + iv.y + iv.z);
    a0 += wt.x * __uint_as_float(t00.x << 16) +
          wt.y * __uint_as_float(t01.x << 16) +
          wt.z * __uint_as_float(t10.x << 16) +
          wt.w * __uint_as_float(t11.x << 16);
    a1 += wt.x * __uint_as_float(t00.x & 0xffff0000u) +
          wt.y * __uint_as_float(t01.x & 0xffff0000u) +
          wt.z * __uint_as_float(t10.x & 0xffff0000u) +
          wt.w * __uint_as_float(t11.x & 0xffff0000u);
    a2 += wt.x * __uint_as_float(t00.y << 16) +
          wt.y * __uint_as_float(t01.y << 16) +
          wt.z * __uint_as_float(t10.y << 16) +
          wt.w * __uint_as_float(t11.y << 16);
    a3 += wt.x * __uint_as_float(t00.y & 0xffff0000u) +
          wt.y * __uint_as_float(t01.y & 0xffff0000u) +
          wt.z * __uint_as_float(t10.y & 0xffff0000u) +
          wt.w * __uint_as_float(t11.y & 0xffff0000u);
  }
  // reduce the 3 pt-subgroups: lane cl needs lanes cl+20, cl+40
  {
    float s0 = __shfl(a0, lane + 20), u0 = __shfl(a0, lane + 40);
    float s1 = __shfl(a1, lane + 20), u1 = __shfl(a1, lane + 40);
    float s2 = __shfl(a2, lane + 20), u2 = __shfl(a2, lane + 40);
    float s3 = __shfl(a3, lane + 20), u3 = __shfl(a3, lane + 40);
    a0 += s0 + u0;
    a1 += s1 + u1;
    a2 += s2 + u2;
    a3 += s3 + u3;
  }
  if (lane < 20) {
    lds[(c4 + 0) * 5 + wv] = a0;
    lds[(c4 + 1) * 5 + wv] = a1;
    lds[(c4 + 2) * 5 + wv] = a2;
    lds[(c4 + 3) * 5 + wv] = a3;
  }
  __syncthreads();
  int tid = threadIdx.x;
  if (tid < NUM_CLASSES) {
    float bb = bias[tid];
    float4 v = {lds[tid * 5] + bb, lds[tid * 5 + 1] + bb, lds[tid * 5 + 2] + bb,
                lds[tid * 5 + 3] + bb};
    int m0 = b * 4;
    int n = m0 / P;
    int p0 = m0 - n * P;
    *(float4*)&out[((size_t)n * NUM_CLASSES + tid) * P + p0] = v;
  }
}

// ---------------------------------------------------------------------- launch
extern "C" void kernel_launch(void* const* d_in, const int* in_sizes, int n_in,
                              void* d_out, int out_size, void* d_ws,
                              size_t ws_size, hipStream_t stream) {
  const float* reg_feat0 = (const float*)d_in[0];
  const float* reg_feat1 = (const float*)d_in[1];
  const float* cls_feat0 = (const float*)d_in[2];
  const float* cls_feat1 = (const float*)d_in[3];
  const float* anchor0 = (const float*)d_in[4];
  const float* anchor1 = (const float*)d_in[5];
  const float* dyn_w = (const float*)d_in[6];
  const float* dyn_b = (const float*)d_in[7];
  const float* reg_w = (const float*)d_in[8];
  const float* cls_w = (const float*)d_in[9];
  const float* cls_b = (const float*)d_in[10];

  float* out = (float*)d_out;
  float* out_cls0 = out;
  float* out_cls1 = out_cls0 + (size_t)N_BATCH * NUM_CLASSES * P0c;
  float* out_coarse0 = out_cls1 + (size_t)N_BATCH * NUM_CLASSES * P1c;
  float* out_coarse1 = out_coarse0 + (size_t)N_BATCH * 4 * P0c;
  float* out_reg0 = out_coarse1 + (size_t)N_BATCH * 4 * P1c;
  float* out_reg1 = out_reg0 + (size_t)N_BATCH * 4 * P0c;

  // ---- workspace layout (bytes)
  char* w = (char*)d_ws;
  __hip_bfloat16* bpack = (__hip_bfloat16*)w;   w += 368640;
  __hip_bfloat16* wpack = (__hip_bfloat16*)w;   w += 221184;
  char* apack_base = w;
  __hip_bfloat16* apack0 = (__hip_bfloat16*)w;  w += 15597568;  // 119*8192*16
  __hip_bfloat16* apack1 = (__hip_bfloat16*)w;  w += 3932160;   // 30*8192*16
  char* rpack_base = w;
  __hip_bfloat16* rpack0 = (__hip_bfloat16*)w;  w += 15597568;  // tiled
  __hip_bfloat16* rpack1 = (__hip_bfloat16*)w;  w += 3932160;
  float* part1 = (float*)w;                     w += 1459200;   // M1*48*4
  __hip_bfloat16* map0 = (__hip_bfloat16*)w;    w += 43776000;  // M0*720*2
  __hip_bfloat16* map1 = (__hip_bfloat16*)w;    w += 10944000;  // M1*720*2
  // part0 (5,836,800 B) aliases apack (dead after gemm; conv runs after gemm).
  float* part0 = (float*)apack_base;
  // gather descriptors alias rpack0+rpack1 (19.5 MB, dead after conv)
  int4* sidx0 = (int4*)rpack_base;
  float4* swt0 = (float4*)(rpack_base + 4377600);
  int4* sidx1 = (int4*)(rpack_base + 8755200);
  float4* swt1 = (float4*)(rpack_base + 9849600);

  hipLaunchKernelGGL(pack_feat, dim3(2528), dim3(256), 0, stream, cls_feat0,
                     cls_feat1, reg_feat0, reg_feat1, cls_w, dyn_w, reg_w,
                     apack0, apack1, rpack0, rpack1, bpack, wpack);
  hipLaunchKernelGGL(cls_gemm_mfma, dim3(8 * 19 * 9), dim3(512), 0, stream,
                     (const uint4*)apack0, (const uint4*)apack1,
                     (const uint4*)bpack, map0, map1);
  hipLaunchKernelGGL(dyn_reg_conv_mfma, dim3(600), dim3(256), 0,
                     stream, (const uint4*)rpack0, (const uint4*)rpack1,
                     (const uint4*)wpack, part0, part1);
  hipLaunchKernelGGL(decode, dim3(600), dim3(64), 0, stream, part0,
                     part1, dyn_b, anchor0, anchor1, out_coarse0, out_coarse1,
                     out_reg0, out_reg1, sidx0, swt0, sidx1, swt1);
  hipLaunchKernelGGL(cls_gather_f, dim3(9504), dim3(256), 0, stream, map0,
                     map1, sidx0, swt0, sidx1, swt1, cls_b, out_cls0, out_cls1);
}

// Round 7
// 217.352 us; speedup vs baseline: 1.0278x; 1.0278x over previous
//
#include <hip/hip_runtime.h>
#include <hip/hip_bf16.h>
#include <cstdint>

#define N_BATCH 2
#define C_IN 256
#define DYN_CH 34
#define CLS_CH 720
#define NUM_CLASSES 80
#define NCOMB 48

#define P0c 15200
#define P1c 3800
#define M0c 30400
#define M1c 7600
#define MT0c 119
#define MT1c 30
#define CT0c 475
#define CT1c 119

typedef __attribute__((ext_vector_type(8))) short short8;   // 8 bf16
typedef __attribute__((ext_vector_type(4))) float f32x4;

typedef const unsigned int __attribute__((address_space(1)))* gas1_t;
typedef unsigned int __attribute__((address_space(3)))* las3_t;

__device__ __forceinline__ void async_ld16(const void* g, void* l) {
  __builtin_amdgcn_global_load_lds((gas1_t)g, (las3_t)l, 16, 0, 0);
}

// ---------------- pack_feat: all 4 feature packs (tiled layout) + weight packs
__global__ __launch_bounds__(256) void pack_feat(
    const float* __restrict__ cls0, const float* __restrict__ cls1,
    const float* __restrict__ reg0, const float* __restrict__ reg1,
    const float* __restrict__ cls_w, const float* __restrict__ dyn_w,
    const float* __restrict__ reg_w, __hip_bfloat16* __restrict__ a0,
    __hip_bfloat16* __restrict__ a1, __hip_bfloat16* __restrict__ r0,
    __hip_bfloat16* __restrict__ r1, __hip_bfloat16* __restrict__ bpack,
    __hip_bfloat16* __restrict__ wpack) {
  int b = blockIdx.x;
  if (b >= 2384) {
    b -= 2384;
    if (b < 90) {  // cls weights -> bpack [ntile][kcg][och]
      int u = b * 256 + threadIdx.x;
      if (u >= 9 * 32 * 80) return;
      int ntile = u / 2560;
      int rem = u % 2560;
      int kcg = rem / 80;
      int ochl = rem % 80;
      int och = ntile * 80 + ochl;
      const float* wr = cls_w + (size_t)och * C_IN + kcg * 8;
      __hip_bfloat16 tmp[8];
#pragma unroll
      for (int c = 0; c < 8; ++c) tmp[c] = __float2bfloat16(wr[c]);
      *(uint4*)(bpack + (size_t)u * 8) = *(const uint4*)tmp;
    } else {  // dyn+reg weights -> wpack swizzled [chunk][n][slot]
      int u = (b - 90) * 256 + threadIdx.x;
      if (u >= 13824) return;
      int j = u / 768;
      int r = u % 768;
      int n = r / 16;
      int s = r % 16;
      int ku = j * 16 + (s ^ (n & 7));
      int k0 = ku * 8;
      int tap = k0 >> 8;
      int c0 = k0 & 255;
      __hip_bfloat16 tmp[8];
#pragma unroll
      for (int i = 0; i < 8; ++i) {
        int c = c0 + i;
        float v = 0.f;
        if (n < DYN_CH) v = dyn_w[((size_t)n * C_IN + c) * 9 + tap];
        else if (n < DYN_CH + 4 && tap == 4)
          v = reg_w[(size_t)(n - DYN_CH) * C_IN + c];
        tmp[i] = __float2bfloat16(v);
      }
      *(uint4*)(wpack + (size_t)u * 8) = *(const uint4*)tmp;
    }
    return;
  }
  int j = b & 7;
  int mtg = b >> 3;
  const float* src;
  __hip_bfloat16* dst;
  int P, Mtot, mtile;
  if (mtg < 119)      { src = cls0; dst = a0; P = P0c; Mtot = M0c; mtile = mtg; }
  else if (mtg < 149) { src = cls1; dst = a1; P = P1c; Mtot = M1c; mtile = mtg - 119; }
  else if (mtg < 268) { src = reg0; dst = r0; P = P0c; Mtot = M0c; mtile = mtg - 149; }
  else                { src = reg1; dst = r1; P = P1c; Mtot = M1c; mtile = mtg - 268; }
  int wave = threadIdx.x >> 6;
  int lane = threadIdx.x & 63;
  int kcg = j * 4 + wave;
  int c0 = kcg * 8;
  int m4 = mtile * 256 + lane * 4;
  uint4* du = (uint4*)dst + (size_t)mtile * 8192 + (size_t)kcg * 256 + lane * 4;
  if (m4 < Mtot) {
    int n = m4 / P;
    int p = m4 - n * P;
    const float* sp = src + ((size_t)n * C_IN + c0) * P + p;
    float4 f[8];
#pragma unroll
    for (int c = 0; c < 8; ++c) f[c] = *(const float4*)(sp + (size_t)c * P);
#pragma unroll
    for (int i = 0; i < 4; ++i) {
      union { uint4 u; __hip_bfloat16 h[8]; } o;
#pragma unroll
      for (int c = 0; c < 8; ++c) {
        float v = (i == 0) ? f[c].x : (i == 1) ? f[c].y : (i == 2) ? f[c].z : f[c].w;
        o.h[c] = __float2bfloat16(v);
      }
      du[i] = o.u;
    }
  } else {
    uint4 z = {0u, 0u, 0u, 0u};
#pragma unroll
    for (int i = 0; i < 4; ++i) du[i] = z;
  }
}

// ---------- dyn3x3 + reg1x1 fused implicit-GEMM MFMA, FULL-K (no split-K).
// Runs FIRST after pack (gemm/decode depend on it downstream). part written
// once, pre-summed. Bijective XCD chunking (74+{0,1} per XCD).
__global__ __launch_bounds__(256) void dyn_reg_conv_mfma(
    const uint4* __restrict__ rp0, const uint4* __restrict__ rp1,
    const uint4* __restrict__ wp, float* __restrict__ part0,
    float* __restrict__ part1) {
  __shared__ uint4 Bs[768];
  int g = blockIdx.x & 7;
  int i = blockIdx.x >> 3;         // [0,75)
  int cnt = 74 + (g < 2 ? 1 : 0);  // 594 = 8*74 + 2
  if (i >= cnt) return;            // block-uniform exit: no barrier hazard
  int bx = g * 74 + (g < 2 ? g : 2) + i;   // [0,594), contiguous per XCD
  int tid = threadIdx.x;
  int wave = tid >> 6;
  int lane = tid & 63;
  int l15 = lane & 15;
  int kq = lane >> 4;

  const uint4* rp;
  float* part;
  int Mtot, P, W, H;
  if (bx < CT0c) { rp = rp0; part = part0; Mtot = M0c; P = P0c; W = 152; H = 100; }
  else { bx -= CT0c; rp = rp1; part = part1; Mtot = M1c; P = P1c; W = 76; H = 50; }

  int m = bx * 64 + wave * 16 + l15;
  bool mval = (m < Mtot);
  int mc = mval ? m : 0;
  int n = mc / P;
  int rem = mc - n * P;
  int y = rem / W;
  int x = rem - y * W;

  f32x4 acc[3];
#pragma unroll
  for (int q = 0; q < 3; ++q) acc[q] = (f32x4)0.f;

  for (int j = 0; j < 18; ++j) {
    const uint4* wsrc = wp + (size_t)j * 768 + wave * 192;
#pragma unroll
    for (int q = 0; q < 3; ++q)
      async_ld16(wsrc + q * 64 + lane, &Bs[wave * 192 + q * 64]);

    int tap = j >> 1;
    int cb8 = (j & 1) * 16;
    int dy = tap / 3 - 1, dx = tap % 3 - 1;
    int sy = y + dy, sx = x + dx;
    bool val = mval && ((unsigned)sy < (unsigned)H) && ((unsigned)sx < (unsigned)W);
    int sm = m + dy * W + dx;
    int smc = val ? sm : 0;
    size_t tbase = (size_t)(smc >> 8) * 8192 + (smc & 255);
    uint4 a[4];
#pragma unroll
    for (int t = 0; t < 4; ++t) {
      uint4 v = {0u, 0u, 0u, 0u};
      if (val) v = rp[tbase + (size_t)(cb8 + t * 4 + kq) * 256];
      a[t] = v;
    }
    __syncthreads();
#pragma unroll
    for (int t = 0; t < 4; ++t) {
#pragma unroll
      for (int ni = 0; ni < 3; ++ni) {
        int nn = ni * 16 + l15;
        short8 bf = *(const short8*)&Bs[nn * 16 + ((t * 4 + kq) ^ (nn & 7))];
        acc[ni] = __builtin_amdgcn_mfma_f32_16x16x32_bf16(
            *(short8*)&a[t], bf, acc[ni], 0, 0, 0);
      }
    }
    __syncthreads();
  }

  int mrow = bx * 64 + wave * 16 + kq * 4;
#pragma unroll
  for (int r = 0; r < 4; ++r) {
    int mm = mrow + r;
    if (mm >= Mtot) continue;
    float* dst = part + (size_t)mm * NCOMB + l15;
#pragma unroll
    for (int ni = 0; ni < 3; ++ni) dst[ni * 16] = acc[ni][r];
  }
}

// -------------------- bilinear sample of combined-map channel (pre-summed)
__device__ __forceinline__ float samp(const float* __restrict__ part,
                                      int nbase, int W, int H,
                                      float px, float py, int ch) {
  float xc = fminf(fmaxf(px, 0.f), (float)(W - 1));
  float yc = fminf(fmaxf(py, 0.f), (float)(H - 1));
  float x0f = floorf(xc), y0f = floorf(yc);
  float fx = xc - x0f, fy = yc - y0f;
  int x0 = (int)x0f, y0 = (int)y0f;
  int x1 = min(x0 + 1, W - 1), y1 = min(y0 + 1, H - 1);
  float v00 = part[(size_t)(nbase + y0 * W + x0) * NCOMB + ch];
  float v01 = part[(size_t)(nbase + y0 * W + x1) * NCOMB + ch];
  float v10 = part[(size_t)(nbase + y1 * W + x0) * NCOMB + ch];
  float v11 = part[(size_t)(nbase + y1 * W + x1) * NCOMB + ch];
  return v00 * (1.f - fx) * (1.f - fy) + v01 * fx * (1.f - fy) +
         v10 * (1.f - fx) * fy + v11 * fx * fy;
}

// ---------------- decode for one 64-px unit u, executed by one wave (lane=px)
__device__ __forceinline__ void decode_unit(
    int u, int lane, const float* __restrict__ part0,
    const float* __restrict__ part1, const float* __restrict__ dyn_b,
    const float* __restrict__ anchor0, const float* __restrict__ anchor1,
    float* __restrict__ out_coarse0, float* __restrict__ out_coarse1,
    float* __restrict__ out_regbox0, float* __restrict__ out_regbox1,
    int4* __restrict__ sidx0, float4* __restrict__ swt0,
    int4* __restrict__ sidx1, float4* __restrict__ swt1) {
  const float* part;
  const float* anchor;
  float* out_coarse;
  float* out_regbox;
  int4* sidx;
  float4* swt;
  int Mtot, H, W, P, level, m;
  if (u < 475) {
    part = part0; anchor = anchor0; out_coarse = out_coarse0;
    out_regbox = out_regbox0; sidx = sidx0; swt = swt0;
    Mtot = M0c; H = 100; W = 152; P = P0c; level = 0;
    m = u * 64 + lane;
  } else {
    part = part1; anchor = anchor1; out_coarse = out_coarse1;
    out_regbox = out_regbox1; sidx = sidx1; swt = swt1;
    Mtot = M1c; H = 50; W = 76; P = P1c; level = 1;
    m = (u - 475) * 64 + lane;
  }
  if (m >= Mtot) return;
  int n = m / P;
  int p = m - n * P;
  float pr[40];
  {
    const float4* q0 = (const float4*)(part + (size_t)m * NCOMB);
#pragma unroll
    for (int o4 = 0; o4 < 10; ++o4) {
      float4 a = q0[o4];
      pr[4 * o4 + 0] = a.x;
      pr[4 * o4 + 1] = a.y;
      pr[4 * o4 + 2] = a.z;
      pr[4 * o4 + 3] = a.w;
    }
#pragma unroll
    for (int o = 0; o < DYN_CH; ++o) pr[o] += dyn_b[o];
  }
  const float* an = anchor + (size_t)n * 4 * P + p;
  float cb[4];
#pragma unroll
  for (int k = 0; k < 4; ++k) cb[k] = an[(size_t)k * P] + pr[k];
  float* oc = out_coarse + (size_t)n * 4 * P + p;
#pragma unroll
  for (int k = 0; k < 4; ++k) oc[(size_t)k * P] = cb[k];

  float thr_y = (cb[3] - cb[1]) * 0.25f;
  float thr_x = (cb[2] - cb[0]) * 0.25f;
  float bo[4];
#pragma unroll
  for (int j = 0; j < 4; ++j) {
    float thr = (j & 1) ? thr_x : thr_y;
    float b = pr[4 + j];
    float extra = fmaxf(b - thr, 0.f) + fminf(b + thr, 0.f);
    bo[j] = b - extra;
  }
  float cx = 0.5f * (cb[0] + cb[2]);
  float cy = 0.5f * (cb[1] + cb[3]);
  float bp[8] = {cb[0], cy + bo[0], cx + bo[1], cb[1],
                 cb[2], cy + bo[2], cx + bo[3], cb[3]};

  int nbase = n * P;
  int nbaseLo = n * P0c;
  float rb[4];
#pragma unroll
  for (int pt = 0; pt < 4; ++pt) {
    float hi = samp(part, nbase, W, H, bp[2 * pt], bp[2 * pt + 1],
                    DYN_CH + pt);
    float val;
    if (level == 0) {
      val = hi;
    } else {
      float lo = 0.5f * samp(part0, nbaseLo, 152, 100, bp[2 * pt] * 2.f,
                             bp[2 * pt + 1] * 2.f, DYN_CH + pt);
      float e0 = pr[26 + 2 * pt], e1 = pr[26 + 2 * pt + 1];
      float mx = fmaxf(e0, e1);
      float w0 = expf(e0 - mx), w1 = expf(e1 - mx);
      val = (lo * w0 + hi * w1) / (w0 + w1);
    }
    rb[pt] = val;
  }
  float* orb = out_regbox + (size_t)n * 4 * P + p;
  orb[0] = bp[0] + rb[0];
  orb[(size_t)P] = bp[3] + rb[1];
  orb[(size_t)2 * P] = bp[4] + rb[2];
  orb[(size_t)3 * P] = bp[7] + rb[3];

  float sx[9] = {cb[0], cb[0], cb[0], cx, cx, cx, cb[2], cb[2], cb[2]};
  float sy[9] = {cb[1], cy, cb[3], cb[1], cy, cb[3], cb[1], cy, cb[3]};
#pragma unroll
  for (int k = 0; k < 9; ++k) {
    float px = sx[k] + pr[8 + 2 * k];
    float py = sy[k] + pr[8 + 2 * k + 1];
    float xc = fminf(fmaxf(px, 0.f), (float)(W - 1));
    float yc = fminf(fmaxf(py, 0.f), (float)(H - 1));
    float x0f = floorf(xc), y0f = floorf(yc);
    float fx = xc - x0f, fy = yc - y0f;
    int x0 = (int)x0f, y0 = (int)y0f;
    int x1 = min(x0 + 1, W - 1), y1 = min(y0 + 1, H - 1);
    int4 iv;
    iv.x = (nbase + y0 * W + x0) * CLS_CH + k * 80;
    iv.y = (x1 - x0) * CLS_CH;
    iv.z = (y1 - y0) * W * CLS_CH;
    iv.w = 0;
    sidx[(size_t)k * Mtot + m] = iv;
    float4 wv = {(1.f - fx) * (1.f - fy), fx * (1.f - fy), (1.f - fx) * fy,
                 fx * fy};
    swt[(size_t)k * Mtot + m] = wv;
  }
}

// =================== FUSED: cls 1x1 GEMM + decode ============================
// gemm (apack/bpack->map) and decode (part->descriptors) are data-independent
// once conv has run. Decode is traffic-light (7 MB in / 11 MB out) vs gemm's
// ~75 MB, so unlike the R4 gemm+conv fusion the L2 interference is negligible;
// decode's ~594 latency-bound waves (un-widenable: 1 thread/px) hide entirely
// under gemm's span.
// blocks [0,1368): gemm (R6-verified path, swapped-operand epilogue).
// blocks [1368,1448): decode, wave=unit; XCD-chunked to match conv partition
// (1368%8==0, so fused block d lands on XCD d%8; XCD g owns conv units
// [g*74+min(g,2), +74+(g<2)) -> part reads stay L2-local). No barriers and
// only wave-uniform exits in the decode path.
__global__ __launch_bounds__(512) void gemm_decode_fused(
    const uint4* __restrict__ Ap0, const uint4* __restrict__ Ap1,
    const uint4* __restrict__ Bp, __hip_bfloat16* __restrict__ out0,
    __hip_bfloat16* __restrict__ out1, const float* __restrict__ part0,
    const float* __restrict__ part1, const float* __restrict__ dyn_b,
    const float* __restrict__ anchor0, const float* __restrict__ anchor1,
    float* __restrict__ out_coarse0, float* __restrict__ out_coarse1,
    float* __restrict__ out_regbox0, float* __restrict__ out_regbox1,
    int4* __restrict__ sidx0, float4* __restrict__ swt0,
    int4* __restrict__ sidx1, float4* __restrict__ swt1) {
  __shared__ uint4 Bsh[2560];
  int tid = threadIdx.x;
  int w = tid >> 6;
  int lane = tid & 63;

  if (blockIdx.x >= 1368) {
    // --------------------------- decode path ---------------------------------
    int d = blockIdx.x - 1368;     // [0,80)
    int g = d & 7;
    int ii = d >> 3;               // [0,10)
    int cnt = 74 + (g < 2 ? 1 : 0);
    int ul = ii * 8 + w;           // unit-local index, wave-uniform
    if (ul >= cnt) return;
    int u = g * 74 + (g < 2 ? g : 2) + ul;
    decode_unit(u, lane, part0, part1, dyn_b, anchor0, anchor1, out_coarse0,
                out_coarse1, out_regbox0, out_regbox1, sidx0, swt0, sidx1,
                swt1);
    return;
  }

  // ------------------------------ gemm path ----------------------------------
  int bb = blockIdx.x;
  int g = bb & 7;
  int loc = bb >> 3;          // [0,171) = 19 mtiles x 9 ntiles
  int lm = loc / 9;
  int ntile = loc - lm * 9;
  int mtile = g * 19 + lm;
  if (mtile >= MT0c + MT1c) return;
  int l15 = lane & 15;
  int kq = lane >> 4;

  const uint4* Ap;
  __hip_bfloat16* out;
  int Mtot;
  if (mtile < MT0c) { Ap = Ap0; out = out0; Mtot = M0c; }
  else              { mtile -= MT0c; Ap = Ap1; out = out1; Mtot = M1c; }

  const uint4* Ab = Ap + (size_t)mtile * 8192;
  const uint4* Bb = Bp + (size_t)ntile * 2560;

  // stage the whole B-ntile once (2560 uint4 = 40 KB)
#pragma unroll
  for (int i = 0; i < 5; ++i)
    async_ld16(Bb + i * 512 + w * 64 + lane, &Bsh[i * 512 + w * 64]);
  __syncthreads();

  f32x4 acc[2][5];
#pragma unroll
  for (int i = 0; i < 2; ++i)
#pragma unroll
    for (int j = 0; j < 5; ++j) acc[i][j] = (f32x4)0.f;

  const uint4* Abase = Ab + kq * 256 + w * 32 + l15;
#pragma unroll 2
  for (int kb = 0; kb < 8; ++kb) {
    uint4 a[2];
#pragma unroll
    for (int mi = 0; mi < 2; ++mi) a[mi] = Abase[kb * 1024 + mi * 16];
    short8 b[5];
    const uint4* Br = &Bsh[kb * 320 + kq * 80 + l15];
#pragma unroll
    for (int ni = 0; ni < 5; ++ni) b[ni] = *(const short8*)&Br[ni * 16];
#pragma unroll
    for (int mi = 0; mi < 2; ++mi)
#pragma unroll
      for (int ni = 0; ni < 5; ++ni)
        acc[mi][ni] = __builtin_amdgcn_mfma_f32_16x16x32_bf16(
            b[ni], *(const short8*)&a[mi], acc[mi][ni], 0, 0, 0);
  }

  // swapped layout: lane (kq,l15) holds och = ni*16 + kq*4 + r for pixel
  // px = gbase + mi*16 + l15 -> 4 adjacent bf16 = 1 uint2 store.
  int gbase = mtile * 256 + w * 32;
#pragma unroll
  for (int mi = 0; mi < 2; ++mi) {
    int px = gbase + mi * 16 + l15;
    if (px >= Mtot) continue;
    __hip_bfloat16* orow = out + (size_t)px * CLS_CH + ntile * 80 + kq * 4;
#pragma unroll
    for (int ni = 0; ni < 5; ++ni) {
      union { uint2 u; __hip_bfloat16 h[4]; } o;
#pragma unroll
      for (int r = 0; r < 4; ++r) o.h[r] = __float2bfloat16(acc[mi][ni][r]);
      *(uint2*)(orow + ni * 16) = o.u;
    }
  }
}

// ------------- gather: wave = 1 px. lane = (pt-subgroup sub=lane/20,
// class-quad cl=lane%20): 60/64 lanes active, uint2 (4-class) map loads,
// 3 outer iters cover 9 pts -> 18 VMEM insts/px-wave.
// Cross-subgroup reduce via 8 shfls (lanes cl, cl+20, cl+40).
__global__ __launch_bounds__(256) void cls_gather_f(
    const __hip_bfloat16* __restrict__ map0,
    const __hip_bfloat16* __restrict__ map1, const int4* __restrict__ sidx0,
    const float4* __restrict__ swt0, const int4* __restrict__ sidx1,
    const float4* __restrict__ swt1, const float* __restrict__ bias,
    float* __restrict__ outc0, float* __restrict__ outc1) {
  __shared__ float lds[NUM_CLASSES * 5];
  int b = (blockIdx.x & 7) * 1188 + (blockIdx.x >> 3);
  if (b >= 9500) return;
  const __hip_bfloat16* map;
  const int4* sidx;
  const float4* swt;
  float* out;
  int Mtot, P;
  if (b < 7600) { map = map0; sidx = sidx0; swt = swt0; out = outc0; Mtot = M0c; P = P0c; }
  else { b -= 7600; map = map1; sidx = sidx1; swt = swt1; out = outc1; Mtot = M1c; P = P1c; }
  int lane = threadIdx.x & 63;
  int wv = threadIdx.x >> 6;
  int m = b * 4 + wv;  // P,M div by 4: no tail, no n-straddle per block

  int sub = lane / 20;
  if (sub > 2) sub = 2;       // lanes 60..63 duplicate sub=2 (results unused)
  int cl = lane % 20;
  int c4 = cl * 4;

  float a0 = 0.f, a1 = 0.f, a2 = 0.f, a3 = 0.f;
#pragma unroll
  for (int g = 0; g < 3; ++g) {
    int pt = g * 3 + sub;
    int4 iv = sidx[(size_t)pt * Mtot + m];
    float4 wt = swt[(size_t)pt * Mtot + m];
    const __hip_bfloat16* pl = map + iv.x + c4;
    uint2 t00 = *(const uint2*)(pl);
    uint2 t01 = *(const uint2*)(pl + iv.y);
    uint2 t10 = *(const uint2*)(pl + iv.z);
    uint2 t11 = *(const uint2*)(pl + iv.y + iv.z);
    a0 += wt.x * __uint_as_float(t00.x << 16) +
          wt.y * __uint_as_float(t01.x << 16) +
          wt.z * __uint_as_float(t10.x << 16) +
          wt.w * __uint_as_float(t11.x << 16);
    a1 += wt.x * __uint_as_float(t00.x & 0xffff0000u) +
          wt.y * __uint_as_float(t01.x & 0xffff0000u) +
          wt.z * __uint_as_float(t10.x & 0xffff0000u) +
          wt.w * __uint_as_float(t11.x & 0xffff0000u);
    a2 += wt.x * __uint_as_float(t00.y << 16) +
          wt.y * __uint_as_float(t01.y << 16) +
          wt.z * __uint_as_float(t10.y << 16) +
          wt.w * __uint_as_float(t11.y << 16);
    a3 += wt.x * __uint_as_float(t00.y & 0xffff0000u) +
          wt.y * __uint_as_float(t01.y & 0xffff0000u) +
          wt.z * __uint_as_float(t10.y & 0xffff0000u) +
          wt.w * __uint_as_float(t11.y & 0xffff0000u);
  }
  // reduce the 3 pt-subgroups: lane cl needs lanes cl+20, cl+40
  {
    float s0 = __shfl(a0, lane + 20), u0 = __shfl(a0, lane + 40);
    float s1 = __shfl(a1, lane + 20), u1 = __shfl(a1, lane + 40);
    float s2 = __shfl(a2, lane + 20), u2 = __shfl(a2, lane + 40);
    float s3 = __shfl(a3, lane + 20), u3 = __shfl(a3, lane + 40);
    a0 += s0 + u0;
    a1 += s1 + u1;
    a2 += s2 + u2;
    a3 += s3 + u3;
  }
  if (lane < 20) {
    lds[(c4 + 0) * 5 + wv] = a0;
    lds[(c4 + 1) * 5 + wv] = a1;
    lds[(c4 + 2) * 5 + wv] = a2;
    lds[(c4 + 3) * 5 + wv] = a3;
  }
  __syncthreads();
  int tid = threadIdx.x;
  if (tid < NUM_CLASSES) {
    float bb = bias[tid];
    float4 v = {lds[tid * 5] + bb, lds[tid * 5 + 1] + bb, lds[tid * 5 + 2] + bb,
                lds[tid * 5 + 3] + bb};
    int m0 = b * 4;
    int n = m0 / P;
    int p0 = m0 - n * P;
    *(float4*)&out[((size_t)n * NUM_CLASSES + tid) * P + p0] = v;
  }
}

// ---------------------------------------------------------------------- launch
extern "C" void kernel_launch(void* const* d_in, const int* in_sizes, int n_in,
                              void* d_out, int out_size, void* d_ws,
                              size_t ws_size, hipStream_t stream) {
  const float* reg_feat0 = (const float*)d_in[0];
  const float* reg_feat1 = (const float*)d_in[1];
  const float* cls_feat0 = (const float*)d_in[2];
  const float* cls_feat1 = (const float*)d_in[3];
  const float* anchor0 = (const float*)d_in[4];
  const float* anchor1 = (const float*)d_in[5];
  const float* dyn_w = (const float*)d_in[6];
  const float* dyn_b = (const float*)d_in[7];
  const float* reg_w = (const float*)d_in[8];
  const float* cls_w = (const float*)d_in[9];
  const float* cls_b = (const float*)d_in[10];

  float* out = (float*)d_out;
  float* out_cls0 = out;
  float* out_cls1 = out_cls0 + (size_t)N_BATCH * NUM_CLASSES * P0c;
  float* out_coarse0 = out_cls1 + (size_t)N_BATCH * NUM_CLASSES * P1c;
  float* out_coarse1 = out_coarse0 + (size_t)N_BATCH * 4 * P0c;
  float* out_reg0 = out_coarse1 + (size_t)N_BATCH * 4 * P1c;
  float* out_reg1 = out_reg0 + (size_t)N_BATCH * 4 * P0c;

  // ---- workspace layout (bytes)
  char* w = (char*)d_ws;
  __hip_bfloat16* bpack = (__hip_bfloat16*)w;   w += 368640;
  __hip_bfloat16* wpack = (__hip_bfloat16*)w;   w += 221184;
  __hip_bfloat16* apack0 = (__hip_bfloat16*)w;  w += 15597568;  // 119*8192*16
  __hip_bfloat16* apack1 = (__hip_bfloat16*)w;  w += 3932160;   // 30*8192*16
  char* rpack_base = w;
  __hip_bfloat16* rpack0 = (__hip_bfloat16*)w;  w += 15597568;  // tiled
  __hip_bfloat16* rpack1 = (__hip_bfloat16*)w;  w += 3932160;
  float* part1 = (float*)w;                     w += 1459200;   // M1*48*4
  __hip_bfloat16* map0 = (__hip_bfloat16*)w;    w += 43776000;  // M0*720*2
  __hip_bfloat16* map1 = (__hip_bfloat16*)w;    w += 10944000;  // M1*720*2
  // part0 has its OWN region: gemm reads apack concurrently with decode
  // reading part0 in the fused kernel -> the old apack alias would race.
  float* part0 = (float*)w;                     w += 5836800;   // M0*48*4
  // gather descriptors alias rpack0+rpack1 (19.5 MB, dead after conv)
  int4* sidx0 = (int4*)rpack_base;
  float4* swt0 = (float4*)(rpack_base + 4377600);
  int4* sidx1 = (int4*)(rpack_base + 8755200);
  float4* swt1 = (float4*)(rpack_base + 9849600);

  hipLaunchKernelGGL(pack_feat, dim3(2528), dim3(256), 0, stream, cls_feat0,
                     cls_feat1, reg_feat0, reg_feat1, cls_w, dyn_w, reg_w,
                     apack0, apack1, rpack0, rpack1, bpack, wpack);
  hipLaunchKernelGGL(dyn_reg_conv_mfma, dim3(600), dim3(256), 0,
                     stream, (const uint4*)rpack0, (const uint4*)rpack1,
                     (const uint4*)wpack, part0, part1);
  hipLaunchKernelGGL(gemm_decode_fused, dim3(1448), dim3(512), 0, stream,
                     (const uint4*)apack0, (const uint4*)apack1,
                     (const uint4*)bpack, map0, map1, part0, part1, dyn_b,
                     anchor0, anchor1, out_coarse0, out_coarse1, out_reg0,
                     out_reg1, sidx0, swt0, sidx1, swt1);
  hipLaunchKernelGGL(cls_gather_f, dim3(9504), dim3(256), 0, stream, map0,
                     map1, sidx0, swt0, sidx1, swt1, cls_b, out_cls0, out_cls1);
}

// Round 8
// 207.485 us; speedup vs baseline: 1.0767x; 1.0476x over previous
//
#include <hip/hip_runtime.h>
#include <hip/hip_bf16.h>
#include <cstdint>

#define N_BATCH 2
#define C_IN 256
#define DYN_CH 34
#define CLS_CH 720
#define NUM_CLASSES 80
#define NCOMB 48

#define P0c 15200
#define P1c 3800
#define M0c 30400
#define M1c 7600
#define MT0c 119
#define MT1c 30
#define CT0c 475
#define CT1c 119

typedef __attribute__((ext_vector_type(8))) short short8;   // 8 bf16
typedef __attribute__((ext_vector_type(4))) float f32x4;

typedef const unsigned int __attribute__((address_space(1)))* gas1_t;
typedef unsigned int __attribute__((address_space(3)))* las3_t;

__device__ __forceinline__ void async_ld16(const void* g, void* l) {
  __builtin_amdgcn_global_load_lds((gas1_t)g, (las3_t)l, 16, 0, 0);
}

// ---------------- pack_feat: all 4 feature packs (tiled layout) + weight packs
__global__ __launch_bounds__(256) void pack_feat(
    const float* __restrict__ cls0, const float* __restrict__ cls1,
    const float* __restrict__ reg0, const float* __restrict__ reg1,
    const float* __restrict__ cls_w, const float* __restrict__ dyn_w,
    const float* __restrict__ reg_w, __hip_bfloat16* __restrict__ a0,
    __hip_bfloat16* __restrict__ a1, __hip_bfloat16* __restrict__ r0,
    __hip_bfloat16* __restrict__ r1, __hip_bfloat16* __restrict__ bpack,
    __hip_bfloat16* __restrict__ wpack) {
  int b = blockIdx.x;
  if (b >= 2384) {
    b -= 2384;
    if (b < 90) {  // cls weights -> bpack [ntile][kcg][och]
      int u = b * 256 + threadIdx.x;
      if (u >= 9 * 32 * 80) return;
      int ntile = u / 2560;
      int rem = u % 2560;
      int kcg = rem / 80;
      int ochl = rem % 80;
      int och = ntile * 80 + ochl;
      const float* wr = cls_w + (size_t)och * C_IN + kcg * 8;
      __hip_bfloat16 tmp[8];
#pragma unroll
      for (int c = 0; c < 8; ++c) tmp[c] = __float2bfloat16(wr[c]);
      *(uint4*)(bpack + (size_t)u * 8) = *(const uint4*)tmp;
    } else {  // dyn+reg weights -> wpack swizzled [chunk][n][slot]
      int u = (b - 90) * 256 + threadIdx.x;
      if (u >= 13824) return;
      int j = u / 768;
      int r = u % 768;
      int n = r / 16;
      int s = r % 16;
      int ku = j * 16 + (s ^ (n & 7));
      int k0 = ku * 8;
      int tap = k0 >> 8;
      int c0 = k0 & 255;
      __hip_bfloat16 tmp[8];
#pragma unroll
      for (int i = 0; i < 8; ++i) {
        int c = c0 + i;
        float v = 0.f;
        if (n < DYN_CH) v = dyn_w[((size_t)n * C_IN + c) * 9 + tap];
        else if (n < DYN_CH + 4 && tap == 4)
          v = reg_w[(size_t)(n - DYN_CH) * C_IN + c];
        tmp[i] = __float2bfloat16(v);
      }
      *(uint4*)(wpack + (size_t)u * 8) = *(const uint4*)tmp;
    }
    return;
  }
  int j = b & 7;
  int mtg = b >> 3;
  const float* src;
  __hip_bfloat16* dst;
  int P, Mtot, mtile;
  if (mtg < 119)      { src = cls0; dst = a0; P = P0c; Mtot = M0c; mtile = mtg; }
  else if (mtg < 149) { src = cls1; dst = a1; P = P1c; Mtot = M1c; mtile = mtg - 119; }
  else if (mtg < 268) { src = reg0; dst = r0; P = P0c; Mtot = M0c; mtile = mtg - 149; }
  else                { src = reg1; dst = r1; P = P1c; Mtot = M1c; mtile = mtg - 268; }
  int wave = threadIdx.x >> 6;
  int lane = threadIdx.x & 63;
  int kcg = j * 4 + wave;
  int c0 = kcg * 8;
  int m4 = mtile * 256 + lane * 4;
  uint4* du = (uint4*)dst + (size_t)mtile * 8192 + (size_t)kcg * 256 + lane * 4;
  if (m4 < Mtot) {
    int n = m4 / P;
    int p = m4 - n * P;
    const float* sp = src + ((size_t)n * C_IN + c0) * P + p;
    float4 f[8];
#pragma unroll
    for (int c = 0; c < 8; ++c) f[c] = *(const float4*)(sp + (size_t)c * P);
#pragma unroll
    for (int i = 0; i < 4; ++i) {
      union { uint4 u; __hip_bfloat16 h[8]; } o;
#pragma unroll
      for (int c = 0; c < 8; ++c) {
        float v = (i == 0) ? f[c].x : (i == 1) ? f[c].y : (i == 2) ? f[c].z : f[c].w;
        o.h[c] = __float2bfloat16(v);
      }
      du[i] = o.u;
    }
  } else {
    uint4 z = {0u, 0u, 0u, 0u};
#pragma unroll
    for (int i = 0; i < 4; ++i) du[i] = z;
  }
}

// ------------------- cls 1x1 bf16 MFMA GEMM -> bf16 map pixel-major [m][720]
// (R7-verified path, standalone again) XCD-aware grid; B-ntile staged once;
// barrier-free K-loop, direct-global A; swapped-operand uint2 epilogue.
__global__ __launch_bounds__(512) void cls_gemm_mfma(
    const uint4* __restrict__ Ap0, const uint4* __restrict__ Ap1,
    const uint4* __restrict__ Bp, __hip_bfloat16* __restrict__ out0,
    __hip_bfloat16* __restrict__ out1) {
  __shared__ uint4 Bsh[2560];
  int bb = blockIdx.x;
  int g = bb & 7;
  int loc = bb >> 3;          // [0,171) = 19 mtiles x 9 ntiles
  int lm = loc / 9;
  int ntile = loc - lm * 9;
  int mtile = g * 19 + lm;
  if (mtile >= MT0c + MT1c) return;
  int tid = threadIdx.x;
  int w = tid >> 6;
  int lane = tid & 63;
  int l15 = lane & 15;
  int kq = lane >> 4;

  const uint4* Ap;
  __hip_bfloat16* out;
  int Mtot;
  if (mtile < MT0c) { Ap = Ap0; out = out0; Mtot = M0c; }
  else              { mtile -= MT0c; Ap = Ap1; out = out1; Mtot = M1c; }

  const uint4* Ab = Ap + (size_t)mtile * 8192;
  const uint4* Bb = Bp + (size_t)ntile * 2560;

#pragma unroll
  for (int i = 0; i < 5; ++i)
    async_ld16(Bb + i * 512 + w * 64 + lane, &Bsh[i * 512 + w * 64]);
  __syncthreads();

  f32x4 acc[2][5];
#pragma unroll
  for (int i = 0; i < 2; ++i)
#pragma unroll
    for (int j = 0; j < 5; ++j) acc[i][j] = (f32x4)0.f;

  const uint4* Abase = Ab + kq * 256 + w * 32 + l15;
#pragma unroll 2
  for (int kb = 0; kb < 8; ++kb) {
    uint4 a[2];
#pragma unroll
    for (int mi = 0; mi < 2; ++mi) a[mi] = Abase[kb * 1024 + mi * 16];
    short8 b[5];
    const uint4* Br = &Bsh[kb * 320 + kq * 80 + l15];
#pragma unroll
    for (int ni = 0; ni < 5; ++ni) b[ni] = *(const short8*)&Br[ni * 16];
#pragma unroll
    for (int mi = 0; mi < 2; ++mi)
#pragma unroll
      for (int ni = 0; ni < 5; ++ni)
        acc[mi][ni] = __builtin_amdgcn_mfma_f32_16x16x32_bf16(
            b[ni], *(const short8*)&a[mi], acc[mi][ni], 0, 0, 0);
  }

  int gbase = mtile * 256 + w * 32;
#pragma unroll
  for (int mi = 0; mi < 2; ++mi) {
    int px = gbase + mi * 16 + l15;
    if (px >= Mtot) continue;
    __hip_bfloat16* orow = out + (size_t)px * CLS_CH + ntile * 80 + kq * 4;
#pragma unroll
    for (int ni = 0; ni < 5; ++ni) {
      union { uint2 u; __hip_bfloat16 h[4]; } o;
#pragma unroll
      for (int r = 0; r < 4; ++r) o.h[r] = __float2bfloat16(acc[mi][ni][r]);
      *(uint2*)(orow + ni * 16) = o.u;
    }
  }
}

// ---------- dyn3x3 + reg1x1 fused implicit-GEMM MFMA, FULL-K. part written
// once, pre-summed. Bijective XCD chunking (74+{0,1} per XCD) matches
// decode_gather's partition.
__global__ __launch_bounds__(256) void dyn_reg_conv_mfma(
    const uint4* __restrict__ rp0, const uint4* __restrict__ rp1,
    const uint4* __restrict__ wp, float* __restrict__ part0,
    float* __restrict__ part1) {
  __shared__ uint4 Bs[768];
  int g = blockIdx.x & 7;
  int i = blockIdx.x >> 3;         // [0,75)
  int cnt = 74 + (g < 2 ? 1 : 0);  // 594 = 8*74 + 2
  if (i >= cnt) return;            // block-uniform exit: no barrier hazard
  int bx = g * 74 + (g < 2 ? g : 2) + i;   // [0,594), contiguous per XCD
  int tid = threadIdx.x;
  int wave = tid >> 6;
  int lane = tid & 63;
  int l15 = lane & 15;
  int kq = lane >> 4;

  const uint4* rp;
  float* part;
  int Mtot, P, W, H;
  if (bx < CT0c) { rp = rp0; part = part0; Mtot = M0c; P = P0c; W = 152; H = 100; }
  else { bx -= CT0c; rp = rp1; part = part1; Mtot = M1c; P = P1c; W = 76; H = 50; }

  int m = bx * 64 + wave * 16 + l15;
  bool mval = (m < Mtot);
  int mc = mval ? m : 0;
  int n = mc / P;
  int rem = mc - n * P;
  int y = rem / W;
  int x = rem - y * W;

  f32x4 acc[3];
#pragma unroll
  for (int q = 0; q < 3; ++q) acc[q] = (f32x4)0.f;

  for (int j = 0; j < 18; ++j) {
    const uint4* wsrc = wp + (size_t)j * 768 + wave * 192;
#pragma unroll
    for (int q = 0; q < 3; ++q)
      async_ld16(wsrc + q * 64 + lane, &Bs[wave * 192 + q * 64]);

    int tap = j >> 1;
    int cb8 = (j & 1) * 16;
    int dy = tap / 3 - 1, dx = tap % 3 - 1;
    int sy = y + dy, sx = x + dx;
    bool val = mval && ((unsigned)sy < (unsigned)H) && ((unsigned)sx < (unsigned)W);
    int sm = m + dy * W + dx;
    int smc = val ? sm : 0;
    size_t tbase = (size_t)(smc >> 8) * 8192 + (smc & 255);
    uint4 a[4];
#pragma unroll
    for (int t = 0; t < 4; ++t) {
      uint4 v = {0u, 0u, 0u, 0u};
      if (val) v = rp[tbase + (size_t)(cb8 + t * 4 + kq) * 256];
      a[t] = v;
    }
    __syncthreads();
#pragma unroll
    for (int t = 0; t < 4; ++t) {
#pragma unroll
      for (int ni = 0; ni < 3; ++ni) {
        int nn = ni * 16 + l15;
        short8 bf = *(const short8*)&Bs[nn * 16 + ((t * 4 + kq) ^ (nn & 7))];
        acc[ni] = __builtin_amdgcn_mfma_f32_16x16x32_bf16(
            *(short8*)&a[t], bf, acc[ni], 0, 0, 0);
      }
    }
    __syncthreads();
  }

  int mrow = bx * 64 + wave * 16 + kq * 4;
#pragma unroll
  for (int r = 0; r < 4; ++r) {
    int mm = mrow + r;
    if (mm >= Mtot) continue;
    float* dst = part + (size_t)mm * NCOMB + l15;
#pragma unroll
    for (int ni = 0; ni < 3; ++ni) dst[ni * 16] = acc[ni][r];
  }
}

// -------------------- bilinear sample of combined-map channel (pre-summed)
__device__ __forceinline__ float samp(const float* __restrict__ part,
                                      int nbase, int W, int H,
                                      float px, float py, int ch) {
  float xc = fminf(fmaxf(px, 0.f), (float)(W - 1));
  float yc = fminf(fmaxf(py, 0.f), (float)(H - 1));
  float x0f = floorf(xc), y0f = floorf(yc);
  float fx = xc - x0f, fy = yc - y0f;
  int x0 = (int)x0f, y0 = (int)y0f;
  int x1 = min(x0 + 1, W - 1), y1 = min(y0 + 1, H - 1);
  float v00 = part[(size_t)(nbase + y0 * W + x0) * NCOMB + ch];
  float v01 = part[(size_t)(nbase + y0 * W + x1) * NCOMB + ch];
  float v10 = part[(size_t)(nbase + y1 * W + x0) * NCOMB + ch];
  float v11 = part[(size_t)(nbase + y1 * W + x1) * NCOMB + ch];
  return v00 * (1.f - fx) * (1.f - fy) + v01 * fx * (1.f - fy) +
         v10 * (1.f - fx) * fy + v11 * fx * fy;
}

// ============== MERGED decode + gather: one block = one 64-px unit ===========
// The descriptor dependency is pixel-local (gather for px m consumes exactly
// decode's sidx/swt[.][m]) -> descriptors live in LDS, never touch global
// (-22 MB traffic, -1 launch boundary, -descriptor-load latency).
// Phase 1: wave 0 decodes 64 px (lane=px; code identical to the verified
//   decode, targets LDS). Waves 1-3 wait -> hidden by other blocks' phase 2.
// Phase 2: 4 waves x 16 rounds; wave=px, lane=(sub=lane/20, cl=lane%20) --
//   the verified 60-lane uint2 gather, descriptors from LDS (broadcast reads).
// Phase 3: staged class-major write via s_out[80][65] (pad 65: scalar LDS
//   writes ~3-way, reads 2-way = free) -> float4-coalesced global stores.
// XCD chunking identical to conv's -> part reads L2-local; map locality
// approx matches gemm's mtile chunking (74*64/256=18.5 vs 19 mtiles/XCD).
__global__ __launch_bounds__(256) void decode_gather(
    const float* __restrict__ part0, const float* __restrict__ part1,
    const float* __restrict__ dyn_b, const float* __restrict__ anchor0,
    const float* __restrict__ anchor1,
    const __hip_bfloat16* __restrict__ map0,
    const __hip_bfloat16* __restrict__ map1, const float* __restrict__ bias,
    float* __restrict__ out_coarse0, float* __restrict__ out_coarse1,
    float* __restrict__ out_regbox0, float* __restrict__ out_regbox1,
    float* __restrict__ outc0, float* __restrict__ outc1) {
  __shared__ int4 s_idx[9][64];
  __shared__ float4 s_wt[9][64];
  __shared__ float s_out[80][65];
  int g = blockIdx.x & 7;
  int ib = blockIdx.x >> 3;        // [0,75)
  int cnt = 74 + (g < 2 ? 1 : 0);
  if (ib >= cnt) return;           // whole-block exit before any barrier
  int u = g * 74 + (g < 2 ? g : 2) + ib;   // [0,594)

  const float* part;
  const float* anchor;
  float* out_coarse;
  float* out_regbox;
  const __hip_bfloat16* map;
  float* outc;
  int Mtot, H, W, P, level, mbase;
  if (u < 475) {
    part = part0; anchor = anchor0; out_coarse = out_coarse0;
    out_regbox = out_regbox0; map = map0; outc = outc0;
    Mtot = M0c; H = 100; W = 152; P = P0c; level = 0; mbase = u * 64;
  } else {
    part = part1; anchor = anchor1; out_coarse = out_coarse1;
    out_regbox = out_regbox1; map = map1; outc = outc1;
    Mtot = M1c; H = 50; W = 76; P = P1c; level = 1; mbase = (u - 475) * 64;
  }
  int tid = threadIdx.x;
  int wv = tid >> 6;
  int lane = tid & 63;

  // ---------------- phase 1: decode (wave 0 only, lane = px)
  if (wv == 0) {
    int m = mbase + lane;
    if (m < Mtot) {
      int n = m / P;
      int p = m - n * P;
      float pr[40];
      {
        const float4* q0 = (const float4*)(part + (size_t)m * NCOMB);
#pragma unroll
        for (int o4 = 0; o4 < 10; ++o4) {
          float4 a = q0[o4];
          pr[4 * o4 + 0] = a.x;
          pr[4 * o4 + 1] = a.y;
          pr[4 * o4 + 2] = a.z;
          pr[4 * o4 + 3] = a.w;
        }
#pragma unroll
        for (int o = 0; o < DYN_CH; ++o) pr[o] += dyn_b[o];
      }
      const float* an = anchor + (size_t)n * 4 * P + p;
      float cb[4];
#pragma unroll
      for (int k = 0; k < 4; ++k) cb[k] = an[(size_t)k * P] + pr[k];
      float* oc = out_coarse + (size_t)n * 4 * P + p;
#pragma unroll
      for (int k = 0; k < 4; ++k) oc[(size_t)k * P] = cb[k];

      float thr_y = (cb[3] - cb[1]) * 0.25f;
      float thr_x = (cb[2] - cb[0]) * 0.25f;
      float bo[4];
#pragma unroll
      for (int j = 0; j < 4; ++j) {
        float thr = (j & 1) ? thr_x : thr_y;
        float b = pr[4 + j];
        float extra = fmaxf(b - thr, 0.f) + fminf(b + thr, 0.f);
        bo[j] = b - extra;
      }
      float cx = 0.5f * (cb[0] + cb[2]);
      float cy = 0.5f * (cb[1] + cb[3]);
      float bp[8] = {cb[0], cy + bo[0], cx + bo[1], cb[1],
                     cb[2], cy + bo[2], cx + bo[3], cb[3]};

      int nbase = n * P;
      int nbaseLo = n * P0c;
      float rb[4];
#pragma unroll
      for (int pt = 0; pt < 4; ++pt) {
        float hi = samp(part, nbase, W, H, bp[2 * pt], bp[2 * pt + 1],
                        DYN_CH + pt);
        float val;
        if (level == 0) {
          val = hi;
        } else {
          float lo = 0.5f * samp(part0, nbaseLo, 152, 100, bp[2 * pt] * 2.f,
                                 bp[2 * pt + 1] * 2.f, DYN_CH + pt);
          float e0 = pr[26 + 2 * pt], e1 = pr[26 + 2 * pt + 1];
          float mx = fmaxf(e0, e1);
          float w0 = expf(e0 - mx), w1 = expf(e1 - mx);
          val = (lo * w0 + hi * w1) / (w0 + w1);
        }
        rb[pt] = val;
      }
      float* orb = out_regbox + (size_t)n * 4 * P + p;
      orb[0] = bp[0] + rb[0];
      orb[(size_t)P] = bp[3] + rb[1];
      orb[(size_t)2 * P] = bp[4] + rb[2];
      orb[(size_t)3 * P] = bp[7] + rb[3];

      float sx[9] = {cb[0], cb[0], cb[0], cx, cx, cx, cb[2], cb[2], cb[2]};
      float sy[9] = {cb[1], cy, cb[3], cb[1], cy, cb[3], cb[1], cy, cb[3]};
#pragma unroll
      for (int k = 0; k < 9; ++k) {
        float px = sx[k] + pr[8 + 2 * k];
        float py = sy[k] + pr[8 + 2 * k + 1];
        float xc = fminf(fmaxf(px, 0.f), (float)(W - 1));
        float yc = fminf(fmaxf(py, 0.f), (float)(H - 1));
        float x0f = floorf(xc), y0f = floorf(yc);
        float fx = xc - x0f, fy = yc - y0f;
        int x0 = (int)x0f, y0 = (int)y0f;
        int x1 = min(x0 + 1, W - 1), y1 = min(y0 + 1, H - 1);
        int4 iv;
        iv.x = (nbase + y0 * W + x0) * CLS_CH + k * 80;
        iv.y = (x1 - x0) * CLS_CH;
        iv.z = (y1 - y0) * W * CLS_CH;
        iv.w = 0;
        s_idx[k][lane] = iv;
        float4 wv4 = {(1.f - fx) * (1.f - fy), fx * (1.f - fy),
                      (1.f - fx) * fy, fx * fy};
        s_wt[k][lane] = wv4;
      }
    }
  }
  __syncthreads();

  // ---------------- phase 2: gather (wave = px, 16 rounds)
  int sub = lane / 20;
  if (sub > 2) sub = 2;            // lanes 60..63 duplicate sub=2 (discarded)
  int cl = lane % 20;
  int c4 = cl * 4;
  for (int r = 0; r < 16; ++r) {
    int pxl = wv * 16 + r;
    int m = mbase + pxl;
    if (m >= Mtot) break;          // wave-uniform (pxl uniform per wave)
    float a0 = 0.f, a1 = 0.f, a2 = 0.f, a3 = 0.f;
#pragma unroll
    for (int gg = 0; gg < 3; ++gg) {
      int pt = gg * 3 + sub;
      int4 iv = s_idx[pt][pxl];    // broadcast within sub-group
      float4 wt = s_wt[pt][pxl];
      const __hip_bfloat16* pl = map + iv.x + c4;
      uint2 t00 = *(const uint2*)(pl);
      uint2 t01 = *(const uint2*)(pl + iv.y);
      uint2 t10 = *(const uint2*)(pl + iv.z);
      uint2 t11 = *(const uint2*)(pl + iv.y + iv.z);
      a0 += wt.x * __uint_as_float(t00.x << 16) +
            wt.y * __uint_as_float(t01.x << 16) +
            wt.z * __uint_as_float(t10.x << 16) +
            wt.w * __uint_as_float(t11.x << 16);
      a1 += wt.x * __uint_as_float(t00.x & 0xffff0000u) +
            wt.y * __uint_as_float(t01.x & 0xffff0000u) +
            wt.z * __uint_as_float(t10.x & 0xffff0000u) +
            wt.w * __uint_as_float(t11.x & 0xffff0000u);
      a2 += wt.x * __uint_as_float(t00.y << 16) +
            wt.y * __uint_as_float(t01.y << 16) +
            wt.z * __uint_as_float(t10.y << 16) +
            wt.w * __uint_as_float(t11.y << 16);
      a3 += wt.x * __uint_as_float(t00.y & 0xffff0000u) +
            wt.y * __uint_as_float(t01.y & 0xffff0000u) +
            wt.z * __uint_as_float(t10.y & 0xffff0000u) +
            wt.w * __uint_as_float(t11.y & 0xffff0000u);
    }
    {  // reduce 3 pt-subgroups: lane cl needs lanes cl+20, cl+40
      float s0 = __shfl(a0, lane + 20), u0 = __shfl(a0, lane + 40);
      float s1 = __shfl(a1, lane + 20), u1 = __shfl(a1, lane + 40);
      float s2 = __shfl(a2, lane + 20), u2 = __shfl(a2, lane + 40);
      float s3 = __shfl(a3, lane + 20), u3 = __shfl(a3, lane + 40);
      a0 += s0 + u0;
      a1 += s1 + u1;
      a2 += s2 + u2;
      a3 += s3 + u3;
    }
    if (lane < 20) {
      s_out[c4 + 0][pxl] = a0;
      s_out[c4 + 1][pxl] = a1;
      s_out[c4 + 2][pxl] = a2;
      s_out[c4 + 3][pxl] = a3;
    }
  }
  __syncthreads();

  // ---------------- phase 3: coalesced class-major write (+bias)
  for (int k = tid; k < 80 * 16; k += 256) {
    int c = k >> 4;                // class
    int q = k & 15;                // px quad
    int m4 = mbase + q * 4;
    if (m4 >= Mtot) continue;      // L1 tail (Mtot%4==0 -> whole quad valid)
    int n = m4 / P;
    int p4 = m4 - n * P;           // P%4==0 -> no n-straddle within quad
    float bb = bias[c];
    float4 v = {s_out[c][q * 4 + 0] + bb, s_out[c][q * 4 + 1] + bb,
                s_out[c][q * 4 + 2] + bb, s_out[c][q * 4 + 3] + bb};
    *(float4*)&outc[((size_t)n * NUM_CLASSES + c) * P + p4] = v;
  }
}

// ---------------------------------------------------------------------- launch
extern "C" void kernel_launch(void* const* d_in, const int* in_sizes, int n_in,
                              void* d_out, int out_size, void* d_ws,
                              size_t ws_size, hipStream_t stream) {
  const float* reg_feat0 = (const float*)d_in[0];
  const float* reg_feat1 = (const float*)d_in[1];
  const float* cls_feat0 = (const float*)d_in[2];
  const float* cls_feat1 = (const float*)d_in[3];
  const float* anchor0 = (const float*)d_in[4];
  const float* anchor1 = (const float*)d_in[5];
  const float* dyn_w = (const float*)d_in[6];
  const float* dyn_b = (const float*)d_in[7];
  const float* reg_w = (const float*)d_in[8];
  const float* cls_w = (const float*)d_in[9];
  const float* cls_b = (const float*)d_in[10];

  float* out = (float*)d_out;
  float* out_cls0 = out;
  float* out_cls1 = out_cls0 + (size_t)N_BATCH * NUM_CLASSES * P0c;
  float* out_coarse0 = out_cls1 + (size_t)N_BATCH * NUM_CLASSES * P1c;
  float* out_coarse1 = out_coarse0 + (size_t)N_BATCH * 4 * P0c;
  float* out_reg0 = out_coarse1 + (size_t)N_BATCH * 4 * P1c;
  float* out_reg1 = out_reg0 + (size_t)N_BATCH * 4 * P0c;

  // ---- workspace layout (bytes)
  char* w = (char*)d_ws;
  __hip_bfloat16* bpack = (__hip_bfloat16*)w;   w += 368640;
  __hip_bfloat16* wpack = (__hip_bfloat16*)w;   w += 221184;
  __hip_bfloat16* apack0 = (__hip_bfloat16*)w;  w += 15597568;  // 119*8192*16
  __hip_bfloat16* apack1 = (__hip_bfloat16*)w;  w += 3932160;   // 30*8192*16
  __hip_bfloat16* rpack0 = (__hip_bfloat16*)w;  w += 15597568;  // tiled
  __hip_bfloat16* rpack1 = (__hip_bfloat16*)w;  w += 3932160;
  float* part1 = (float*)w;                     w += 1459200;   // M1*48*4
  __hip_bfloat16* map0 = (__hip_bfloat16*)w;    w += 43776000;  // M0*720*2
  __hip_bfloat16* map1 = (__hip_bfloat16*)w;    w += 10944000;  // M1*720*2
  float* part0 = (float*)w;                     w += 5836800;   // M0*48*4

  hipLaunchKernelGGL(pack_feat, dim3(2528), dim3(256), 0, stream, cls_feat0,
                     cls_feat1, reg_feat0, reg_feat1, cls_w, dyn_w, reg_w,
                     apack0, apack1, rpack0, rpack1, bpack, wpack);
  hipLaunchKernelGGL(cls_gemm_mfma, dim3(8 * 19 * 9), dim3(512), 0, stream,
                     (const uint4*)apack0, (const uint4*)apack1,
                     (const uint4*)bpack, map0, map1);
  hipLaunchKernelGGL(dyn_reg_conv_mfma, dim3(600), dim3(256), 0,
                     stream, (const uint4*)rpack0, (const uint4*)rpack1,
                     (const uint4*)wpack, part0, part1);
  hipLaunchKernelGGL(decode_gather, dim3(600), dim3(256), 0, stream, part0,
                     part1, dyn_b, anchor0, anchor1, map0, map1, cls_b,
                     out_coarse0, out_coarse1, out_reg0, out_reg1, out_cls0,
                     out_cls1);
}